// Round 11
// baseline (28.889 us; speedup 1.0000x reference)
//
#include <hip/hip_runtime.h>

#define NR 1024
#define DX 256
#define HX 512

typedef __bf16 bf16x8 __attribute__((ext_vector_type(8)));
typedef float  f32x4  __attribute__((ext_vector_type(4)));

// ---- ws byte offsets (atomic accumulators; zeroed via hipMemsetAsync each call)
#define B_TOT 0u      // u64 fixed-point Sigma mu.Y (scale 2^40)
#define B_CTR 8u      // u32 completion counter
#define B_SMU 64u     // u64[2][256] colsum(mu) per mlp (scale 2^32)
#define B_SY  4160u   // u64[2][256] colsum(Y)  per mlp (scale 2^32)
#define B_END 8256u

#define FIX40 1099511627776.0
#define FIX32 4294967296.0

__device__ __forceinline__ unsigned short bf16rne(float x) {
    unsigned int u = __float_as_uint(x);
    u = u + 0x7FFFu + ((u >> 16) & 1u);
    return (unsigned short)(u >> 16);
}
__device__ __forceinline__ float bf16f(unsigned short h) {
    return __uint_as_float(((unsigned int)h) << 16);
}

// bf16 LDS tile [rows][64 k], 128 B/row, 16B-slot swizzle:
// elem (r,k) at byte r*128 + (((k>>3)^(r&7))<<4) + ((k&7)<<1)   (proven R5-R10)
__device__ __forceinline__ uint4 ldsfrag(const unsigned short* lds, int row, int kc, int ln)
{
    const int slot = ((kc >> 3) + (ln >> 4)) ^ (row & 7);
    return *(const uint4*)((const char*)lds + row * 128 + slot * 16);
}

#define MFMA(a, b, c) __builtin_amdgcn_mfma_f32_16x16x32_bf16(                \
    __builtin_bit_cast(bf16x8, a), __builtin_bit_cast(bf16x8, b), c, 0, 0, 0)

// ---------------------------------------------------------------------------
// Phase A: Hid(32x128) = relu(A(32xK) @ W1[:,hc0..hc0+128) + b1). Double-
// buffered reg-convert staging (R10-k1 schedule). Result written to sHid
// (hi/lo, 2 k-tiles of [32][64]) which aliases the dead A buffers.
// LDS map (bytes): [0,16384) A bufs (buf b at b*8192: hi 4K, lo 4K) -> sHid
//                  [16384,49152) W bufs (buf b at 16384+b*16384) -> sW2
template<int NK>
__device__ __forceinline__ void phaseA(
    const float* __restrict__ H, const float* __restrict__ P,
    const float* __restrict__ Wh, const float* __restrict__ bb,
    char* smem, int m0, int hc0, int wv, int ln, int t)
{
    float4 aR[2][2];
    float  wR[2][32];
    const int arow = t >> 3;              // 0..31
    const int aq   = t & 7;               // float4 idx base within 64-k row
    const int wn   = (wv & 1) * 64 + ln;  // 0..127 (n within chunk)
    const int wkh  = (wv >> 1) * 32;      // k-half within 64-k tile

    auto loadA = [&](int rb, int c) {
        const float* src = (NK == 8 && c >= 4) ? P : H;
        const float* p = src + (size_t)(m0 + arow) * DX + (c & 3) * 64 + aq * 4;
        aR[rb][0] = *(const float4*)p;
        aR[rb][1] = *(const float4*)(p + 32);
    };
    auto loadW = [&](int rb, int c) {
        const float* wp = Wh + (size_t)(c * 64 + wkh) * HX + hc0 + wn;
        #pragma unroll
        for (int j = 0; j < 32; ++j) wR[rb][j] = wp[(size_t)j * HX];
    };
    auto writeAW = [&](int rb, int b) {
        char* ah = smem + b * 8192;
        char* al = smem + b * 8192 + 4096;
        #pragma unroll
        for (int i = 0; i < 2; ++i) {
            const int q = aq + i * 8;
            const int byo = arow * 128 + (((q >> 1) ^ (arow & 7)) << 4) + ((q & 1) << 3);
            const float4 v = aR[rb][i];
            const unsigned short h0 = bf16rne(v.x), h1 = bf16rne(v.y),
                                 h2 = bf16rne(v.z), h3 = bf16rne(v.w);
            *(ushort4*)(ah + byo) = make_ushort4(h0, h1, h2, h3);
            *(ushort4*)(al + byo) = make_ushort4(bf16rne(v.x - bf16f(h0)),
                                                 bf16rne(v.y - bf16f(h1)),
                                                 bf16rne(v.z - bf16f(h2)),
                                                 bf16rne(v.w - bf16f(h3)));
        }
        char* wl = smem + 16384 + b * 16384;
        #pragma unroll
        for (int s = 0; s < 8; ++s) {
            const int k4 = wkh + s * 4;
            const int byo = wn * 128 + (((k4 >> 3) ^ (wn & 7)) << 4) + ((k4 & 7) << 1);
            *(ushort4*)(wl + byo) = make_ushort4(
                bf16rne(wR[rb][s*4+0]), bf16rne(wR[rb][s*4+1]),
                bf16rne(wR[rb][s*4+2]), bf16rne(wR[rb][s*4+3]));
        }
    };

    f32x4 zero = {0.f, 0.f, 0.f, 0.f};
    f32x4 acc[2][2] = {{zero, zero}, {zero, zero}};

    loadA(0, 0); loadW(0, 0);
    writeAW(0, 0);
    loadA(1, 1); loadW(1, 1);
    __syncthreads();

    #pragma unroll
    for (int c = 0; c < NK; ++c) {
        const int b = c & 1;
        const unsigned short* ah = (const unsigned short*)(smem + b * 8192);
        const unsigned short* al = (const unsigned short*)(smem + b * 8192 + 4096);
        const unsigned short* wl = (const unsigned short*)(smem + 16384 + b * 16384);
        #pragma unroll
        for (int kc = 0; kc < 64; kc += 32) {
            uint4 fh[2], fl[2], fw[2];
            #pragma unroll
            for (int s = 0; s < 2; ++s) {
                fh[s] = ldsfrag(ah, 16 * s + (ln & 15), kc, ln);
                fl[s] = ldsfrag(al, 16 * s + (ln & 15), kc, ln);
                fw[s] = ldsfrag(wl, 32 * wv + 16 * s + (ln & 15), kc, ln);
            }
            #pragma unroll
            for (int sr = 0; sr < 2; ++sr)
                #pragma unroll
                for (int sc = 0; sc < 2; ++sc) {
                    acc[sr][sc] = MFMA(fh[sr], fw[sc], acc[sr][sc]);
                    acc[sr][sc] = MFMA(fl[sr], fw[sc], acc[sr][sc]);
                }
        }
        if (c + 1 < NK) {
            writeAW(1 - b, 1 - b);
            if (c + 2 < NK) { loadA(b, c + 2); loadW(b, c + 2); }
        }
        __syncthreads();
    }

    // epilogue: +b1, relu, convert hi/lo -> sHid (aliases dead A bufs)
    char* hh = smem;            // hi: kt*4096
    char* hl = smem + 8192;     // lo
    #pragma unroll
    for (int sc = 0; sc < 2; ++sc) {
        const int C = wv * 32 + sc * 16 + (ln & 15);   // 0..127
        const float bv = bb[hc0 + C];
        const int kt = C >> 6, Ck = C & 63;
        #pragma unroll
        for (int sr = 0; sr < 2; ++sr)
            #pragma unroll
            for (int r = 0; r < 4; ++r) {
                const int R = sr * 16 + 4 * (ln >> 4) + r;
                const float v = fmaxf(acc[sr][sc][r] + bv, 0.f);
                const unsigned short h = bf16rne(v);
                const int byo = R * 128 + (((Ck >> 3) ^ (R & 7)) << 4) + ((Ck & 7) << 1);
                *(unsigned short*)(hh + kt * 4096 + byo) = h;
                *(unsigned short*)(hl + kt * 4096 + byo) = bf16rne(v - bf16f(h));
            }
    }
    __syncthreads();
}

// ---------------------------------------------------------------------------
// Single fused kernel. 256 blocks: bx = [mlp:1][chunk:2][slab:5].
// Block owns rows m0..m0+31, hidden cols hc0..hc0+127 of one MLP.
__global__ __launch_bounds__(256) void fused(
    const float* __restrict__ H, const float* __restrict__ P, const float* __restrict__ G,
    const float* __restrict__ W1, const float* __restrict__ b1,
    const float* __restrict__ W1g, const float* __restrict__ b1g,
    const float* __restrict__ W2, const float* __restrict__ W2g,
    char* __restrict__ wsb, float* __restrict__ out)
{
    __shared__ char smem[49152];
    __shared__ float red[256];
    __shared__ double dred[256];
    __shared__ int lastFlag;

    const int bx = blockIdx.x, t = threadIdx.x;
    const int mlp   = bx >> 7;
    const int chunk = (bx >> 5) & 3;
    const int slab  = bx & 31;
    const int m0  = slab * 32;
    const int hc0 = chunk * 128;
    const int wv = t >> 6, ln = t & 63;

    const float* Y = mlp ? G : P;
    unsigned long long* SMU = (unsigned long long*)(wsb + B_SMU) + mlp * 256;
    unsigned long long* SYA = (unsigned long long*)(wsb + B_SY)  + mlp * 256;
    unsigned long long* TOT = (unsigned long long*)(wsb + B_TOT);
    unsigned* CTR = (unsigned*)(wsb + B_CTR);

    // SY colsum for this block's 32 rows (chunk-0 blocks only, no duplication)
    if (chunk == 0) {
        float sy = 0.f;
        #pragma unroll 8
        for (int r = 0; r < 32; ++r) sy += Y[(size_t)(m0 + r) * DX + t];
        atomicAdd(SYA + t, (unsigned long long)llrint((double)sy * FIX32));
    }

    // ---- Phase A: hidden chunk in LDS
    if (mlp) phaseA<8>(H, P, W1g, b1g, smem, m0, hc0, wv, ln, t);
    else     phaseA<4>(H, P, W1,  b1,  smem, m0, hc0, wv, ln, t);

    // ---- Phase B: mu_part(32x256) = (HidH+HidL)(32x128) @ W2[hc0..hc0+128)
    const float* W2p = mlp ? W2g : W2;
    char* sw2 = smem + 16384;              // [256 n][64 k] bf16, 32 KB (dead W1 bufs)
    f32x4 zero = {0.f, 0.f, 0.f, 0.f};
    f32x4 accB[2][4] = {{zero, zero, zero, zero}, {zero, zero, zero, zero}};

    #pragma unroll
    for (int ck = 0; ck < 2; ++ck) {
        // stage W2 tile: thread t owns col n=t, k = ck*64..+63 (coalesced in n)
        #pragma unroll
        for (int g = 0; g < 4; ++g) {
            float w16[16];
            #pragma unroll
            for (int j = 0; j < 16; ++j)
                w16[j] = W2p[(size_t)(hc0 + ck * 64 + g * 16 + j) * DX + t];
            #pragma unroll
            for (int s = 0; s < 4; ++s) {
                const int k4 = g * 16 + s * 4;
                const int byo = t * 128 + (((k4 >> 3) ^ (t & 7)) << 4) + ((k4 & 7) << 1);
                *(ushort4*)(sw2 + byo) = make_ushort4(
                    bf16rne(w16[s*4+0]), bf16rne(w16[s*4+1]),
                    bf16rne(w16[s*4+2]), bf16rne(w16[s*4+3]));
            }
        }
        __syncthreads();
        const unsigned short* hh = (const unsigned short*)(smem + ck * 4096);
        const unsigned short* hl = (const unsigned short*)(smem + 8192 + ck * 4096);
        #pragma unroll
        for (int kc = 0; kc < 64; kc += 32) {
            uint4 fh[2], fl[2], fw[4];
            #pragma unroll
            for (int s = 0; s < 2; ++s) {
                fh[s] = ldsfrag(hh, 16 * s + (ln & 15), kc, ln);
                fl[s] = ldsfrag(hl, 16 * s + (ln & 15), kc, ln);
            }
            #pragma unroll
            for (int sc = 0; sc < 4; ++sc)
                fw[sc] = ldsfrag((const unsigned short*)sw2,
                                 64 * wv + 16 * sc + (ln & 15), kc, ln);
            #pragma unroll
            for (int sr = 0; sr < 2; ++sr)
                #pragma unroll
                for (int sc = 0; sc < 4; ++sc) {
                    accB[sr][sc] = MFMA(fh[sr], fw[sc], accB[sr][sc]);
                    accB[sr][sc] = MFMA(fl[sr], fw[sc], accB[sr][sc]);
                }
        }
        __syncthreads();
    }

    // ---- dot with Y + colsum(mu) atomics
    float part = 0.f;
    #pragma unroll
    for (int sc = 0; sc < 4; ++sc) {
        const int C = wv * 64 + sc * 16 + (ln & 15);
        float colv = 0.f;
        #pragma unroll
        for (int sr = 0; sr < 2; ++sr)
            #pragma unroll
            for (int r = 0; r < 4; ++r) {
                const int R = m0 + sr * 16 + 4 * (ln >> 4) + r;
                const float mu = accB[sr][sc][r];
                part += mu * Y[(size_t)R * DX + C];
                colv += mu;
            }
        colv += __shfl_xor(colv, 16, 64);
        colv += __shfl_xor(colv, 32, 64);
        if ((ln >> 4) == 0)
            atomicAdd(SMU + wv * 64 + sc * 16 + ln,
                      (unsigned long long)llrint((double)colv * FIX32));
    }
    red[t] = part;
    __syncthreads();
    #pragma unroll
    for (int s = 128; s > 0; s >>= 1) {
        if (t < s) red[t] += red[t + s];
        __syncthreads();
    }
    if (t == 0)
        atomicAdd(TOT, (unsigned long long)llrint((double)red[0] * FIX40));

    // ---- fence-free finish: barrier drains all waves' atomics, then ctr++
    __syncthreads();
    if (t == 0) {
        asm volatile("s_waitcnt vmcnt(0)" ::: "memory");
        const unsigned prev = atomicAdd(CTR, 1u);
        lastFlag = (prev == 255u) ? 1 : 0;
    }
    __syncthreads();
    if (lastFlag) {
        unsigned long long* SM0 = (unsigned long long*)(wsb + B_SMU);
        unsigned long long* SY0 = (unsigned long long*)(wsb + B_SY);
        const unsigned long long a0 = atomicAdd(SM0 + t, 0ull);
        const unsigned long long a1 = atomicAdd(SM0 + 256 + t, 0ull);
        const unsigned long long c0 = atomicAdd(SY0 + t, 0ull);
        const unsigned long long c1 = atomicAdd(SY0 + 256 + t, 0ull);
        dred[t] = (double)(long long)a0 * (double)(long long)c0
                + (double)(long long)a1 * (double)(long long)c1;
        __syncthreads();
        #pragma unroll
        for (int s = 128; s > 0; s >>= 1) {
            if (t < s) dred[t] += dred[t + s];
            __syncthreads();
        }
        if (t == 0) {
            const double T1 = (double)(long long)atomicAdd(TOT, 0ull) * (1.0 / FIX40);
            const double T2 = dred[0] * (1.0 / FIX32) * (1.0 / FIX32);
            out[0] = (float)((T1 - T2 * (1.0 / NR)) * (1.0 / NR));
        }
    }
}

// ---------------------------------------------------------------------------
extern "C" void kernel_launch(void* const* d_in, const int* in_sizes, int n_in,
                              void* d_out, int out_size, void* d_ws, size_t ws_size,
                              hipStream_t stream)
{
    const float* H   = (const float*)d_in[0];
    const float* P   = (const float*)d_in[1];
    const float* G   = (const float*)d_in[2];
    const float* W1  = (const float*)d_in[3];
    const float* b1  = (const float*)d_in[4];
    const float* W2  = (const float*)d_in[5];
    // d_in[6] = b2: provably zero contribution against column-centered Y
    const float* W1g = (const float*)d_in[7];
    const float* b1g = (const float*)d_in[8];
    const float* W2g = (const float*)d_in[9];
    // d_in[10] = b2g: unused
    char* wsb = (char*)d_ws;
    float* out = (float*)d_out;

    hipMemsetAsync(d_ws, 0, B_END, stream);   // zero atomic accumulators each call
    hipLaunchKernelGGL(fused, dim3(256), dim3(256), 0, stream,
                       H, P, G, W1, b1, W1g, b1g, W2, W2g, wsb, out);
}

// Round 12
// 26.816 us; speedup vs baseline: 1.0773x; 1.0773x over previous
//
#include <hip/hip_runtime.h>

#define NR 1024
#define DX 256
#define HX 512

typedef __bf16 bf16x8 __attribute__((ext_vector_type(8)));
typedef float  f32x4  __attribute__((ext_vector_type(4)));

// ---- ws byte offsets (~4.3 MB used)
#define B_CM    0u         // f32 [2][16][256] raw column sums per 64-row stripe
#define B_CTR   36864u     // u32 completion counter (reset by k1 each call)
#define B_TOT   36928u     // u64 fixed-point grand total (reset by k1 each call)
#define B_H1H   65536u     // ushort [1024][512] Hid1 hi (1 MB)
#define B_H1L   1114112u   // Hid1 lo
#define B_HGH   2162688u   // Hidg hi
#define B_HGL   3211264u   // Hidg lo

#define FIXSCALE 1099511627776.0   // 2^40

#define GLDS16(gp, lp) __builtin_amdgcn_global_load_lds(                     \
    (const __attribute__((address_space(1))) void*)(gp),                     \
    (__attribute__((address_space(3))) void*)(lp), 16, 0, 0)

__device__ __forceinline__ unsigned short bf16rne(float x) {
    unsigned int u = __float_as_uint(x);
    u = u + 0x7FFFu + ((u >> 16) & 1u);
    return (unsigned short)(u >> 16);
}
__device__ __forceinline__ float bf16f(unsigned short h) {
    return __uint_as_float(((unsigned int)h) << 16);
}

// bf16 LDS tile [64 rows][64 k], 128 B/row, 16B-slot swizzle:
// elem (r,k) at byte r*128 + (((k>>3)^(r&7))<<4) + ((k&7)<<1).
__device__ __forceinline__ uint4 ldsfrag(const unsigned short* lds, int row, int kc, int ln)
{
    const int slot = ((kc >> 3) + (ln >> 4)) ^ (row & 7);
    return *(const uint4*)((const char*)lds + row * 128 + slot * 16);
}

// Stage a 64x64-bf16 tile (row stride ld) via global_load_lds, swizzle applied
// by permuting the per-lane GLOBAL source (LDS dst stays linear, rule 21).
__device__ __forceinline__ void stage_bf16(const unsigned short* src, int r0, int c0,
                                           int ld, unsigned short* lds, int wv, int ln)
{
    const int gsl = (ln & 7) ^ ((ln >> 3) & 7);
    #pragma unroll
    for (int i = 0; i < 2; ++i) {
        const int ins = wv * 2 + i;
        const unsigned short* gp =
            src + (size_t)(r0 + ins * 8 + (ln >> 3)) * ld + c0 + gsl * 8;
        GLDS16(gp, lds + ins * 512);
    }
}

#define MFMA(a, b, c) __builtin_amdgcn_mfma_f32_16x16x32_bf16(                \
    __builtin_bit_cast(bf16x8, a), __builtin_bit_cast(bf16x8, b), c, 0, 0, 0)

// ---------------------------------------------------------------------------
// Hidden GEMM body with in-pipeline fp32->bf16(hi/lo) conversion.
// Tile 64x64, NC 64-k steps. Double-buffered LDS, one barrier per step:
//   iter c: MFMA(buf b) || convert+ds_write buf 1-b (data c+1, regs loaded
//   at iter c-1) || issue global loads for c+2.
template<int NC>
__device__ __forceinline__ void hidden_body(
    const float* __restrict__ A0, const float* __restrict__ A1,
    const float* __restrict__ Wsrc, const float* __restrict__ bb,
    unsigned short* __restrict__ oh, unsigned short* __restrict__ ol,
    unsigned short (*sAh)[4096], unsigned short (*sAl)[4096],
    unsigned short (*sW)[4096],
    int m0, int n0, int wv, int ln)
{
    const int wr = wv >> 1, wc = wv & 1;

    float4 aR[2][4];   // A fp32: rows wv*16+i*4+(ln>>4), cols (ln&15)*4..+3
    float  wR[2][16];  // W fp32: n = n0+ln, k(tile) = wv*16+j  (coalesced in n)

    auto loadA = [&](int rb, int c) {
        const float* src = (NC == 8 && c >= 4) ? A1 : A0;
        const int ac = (c & 3) * 64;
        #pragma unroll
        for (int i = 0; i < 4; ++i)
            aR[rb][i] = *(const float4*)(src +
                (size_t)(m0 + wv * 16 + i * 4 + (ln >> 4)) * DX + ac + (ln & 15) * 4);
    };
    auto loadW = [&](int rb, int c) {
        #pragma unroll
        for (int j = 0; j < 16; ++j)
            wR[rb][j] = Wsrc[(size_t)(c * 64 + wv * 16 + j) * HX + n0 + ln];
    };
    auto writeT = [&](int rb, int b) {
        #pragma unroll
        for (int i = 0; i < 4; ++i) {
            const int r = wv * 16 + i * 4 + (ln >> 4);
            const int q = ln & 15;    // float4 index in row; k = 4q..4q+3
            const int byo = r * 128 + ((((q >> 1) ^ (r & 7))) << 4) + ((q & 1) << 3);
            const float4 v = aR[rb][i];
            const unsigned short h0 = bf16rne(v.x), h1 = bf16rne(v.y),
                                 h2 = bf16rne(v.z), h3 = bf16rne(v.w);
            *(ushort4*)((char*)sAh[b] + byo) = make_ushort4(h0, h1, h2, h3);
            *(ushort4*)((char*)sAl[b] + byo) =
                make_ushort4(bf16rne(v.x - bf16f(h0)), bf16rne(v.y - bf16f(h1)),
                             bf16rne(v.z - bf16f(h2)), bf16rne(v.w - bf16f(h3)));
        }
        #pragma unroll
        for (int s = 0; s < 2; ++s) {   // row ln, k = wv*16+s*8 .. +7 (transpose)
            const int byo = ln * 128 + ((((2 * wv + s) ^ (ln & 7))) << 4);
            *(ushort4*)((char*)sW[b] + byo) =
                make_ushort4(bf16rne(wR[rb][s*8+0]), bf16rne(wR[rb][s*8+1]),
                             bf16rne(wR[rb][s*8+2]), bf16rne(wR[rb][s*8+3]));
            *(ushort4*)((char*)sW[b] + byo + 8) =
                make_ushort4(bf16rne(wR[rb][s*8+4]), bf16rne(wR[rb][s*8+5]),
                             bf16rne(wR[rb][s*8+6]), bf16rne(wR[rb][s*8+7]));
        }
    };

    f32x4 zero = {0.f, 0.f, 0.f, 0.f};
    f32x4 acc[2][2] = {{zero, zero}, {zero, zero}};

    loadA(0, 0); loadW(0, 0);
    writeT(0, 0);                 // compiler waits the c=0 loads
    loadA(1, 1); loadW(1, 1);     // prefetch c=1 under first MFMA phase
    __syncthreads();

    #pragma unroll
    for (int c = 0; c < NC; ++c) {
        const int b = c & 1;
        #pragma unroll
        for (int kc = 0; kc < 64; kc += 32) {
            uint4 fh[2], fl[2], fw[2];
            #pragma unroll
            for (int s = 0; s < 2; ++s) {
                const int ra = 32 * wr + 16 * s + (ln & 15);
                fh[s] = ldsfrag(sAh[b], ra, kc, ln);
                fl[s] = ldsfrag(sAl[b], ra, kc, ln);
                fw[s] = ldsfrag(sW[b], 32 * wc + 16 * s + (ln & 15), kc, ln);
            }
            #pragma unroll
            for (int sr = 0; sr < 2; ++sr)
                #pragma unroll
                for (int sc = 0; sc < 2; ++sc) {
                    acc[sr][sc] = MFMA(fh[sr], fw[sc], acc[sr][sc]);
                    acc[sr][sc] = MFMA(fl[sr], fw[sc], acc[sr][sc]);
                }
        }
        if (c + 1 < NC) {
            writeT(1 - b, 1 - b);                       // data c+1 -> buf 1-b
            if (c + 2 < NC) { loadA(b, c + 2); loadW(b, c + 2); }
        }
        __syncthreads();
    }

    #pragma unroll
    for (int sc = 0; sc < 2; ++sc) {
        const int C = n0 + 32 * wc + 16 * sc + (ln & 15);
        const float bv = bb[C];
        #pragma unroll
        for (int sr = 0; sr < 2; ++sr)
            #pragma unroll
            for (int r = 0; r < 4; ++r) {
                const int R = m0 + 32 * wr + 16 * sr + 4 * (ln >> 4) + r;
                float v = fmaxf(acc[sr][sc][r] + bv, 0.f);
                const unsigned short h = bf16rne(v);
                oh[(size_t)R * 512 + C] = h;
                ol[(size_t)R * 512 + C] = bf16rne(v - bf16f(h));
            }
    }
}

// ---------------------------------------------------------------------------
// K1: hidden GEMM (fused conversion). 256 blocks: [0,128) MLP1, [128,256) MLPg.
// Blocks 0..31 (short mlp0 blocks) additionally compute colmean stripes.
__global__ __launch_bounds__(256) void k1_hidden(
    const float* __restrict__ H, const float* __restrict__ P, const float* __restrict__ G,
    const float* __restrict__ W1, const float* __restrict__ b1,
    const float* __restrict__ W1g, const float* __restrict__ b1g,
    char* __restrict__ wsb)
{
    __shared__ unsigned short sAh[2][4096], sAl[2][4096], sW[2][4096];
    const int bx = blockIdx.x, t = threadIdx.x;
    if (bx == 0 && t == 0) {
        *(unsigned*)(wsb + B_CTR) = 0u;
        *(unsigned long long*)(wsb + B_TOT) = 0ull;
    }
    const int mlp = bx >> 7, bi = bx & 127;
    const int m0 = (bi >> 3) * 64, n0 = (bi & 7) * 64;
    const int wv = t >> 6, ln = t & 63;

    if (mlp)
        hidden_body<8>(H, P, W1g, b1g,
                       (unsigned short*)(wsb + B_HGH), (unsigned short*)(wsb + B_HGL),
                       sAh, sAl, sW, m0, n0, wv, ln);
    else
        hidden_body<4>(H, P, W1, b1,
                       (unsigned short*)(wsb + B_H1H), (unsigned short*)(wsb + B_H1L),
                       sAh, sAl, sW, m0, n0, wv, ln);

    if (bx < 32) {   // colmean raw partials: 64 rows of P (bx<16) or G, col t
        const int cb = bx;
        const float* M = (cb & 16) ? G : P;
        const float* p = M + (size_t)(cb & 15) * 64 * DX + t;
        float s0 = 0.f, s1 = 0.f, s2 = 0.f, s3 = 0.f;
        #pragma unroll 4
        for (int r = 0; r < 64; r += 4) {
            s0 += p[(r + 0) * DX]; s1 += p[(r + 1) * DX];
            s2 += p[(r + 2) * DX]; s3 += p[(r + 3) * DX];
        }
        ((float*)(wsb + B_CM))[((cb >> 4) * 16 + (cb & 15)) * 256 + t] = (s0 + s1) + (s2 + s3);
    }
}

// ---------------------------------------------------------------------------
// K2: mu = Hid @ W2 (b2 contributes exactly 0 against centered Y) dotted with
// (Y - colmean(Y)) on the fly. Hid staged via global_load_lds (already bf16);
// W2 reg-converted in-pipeline. Fence-free fixed-point atomic finish (R9).
// 256 blocks: bx = [mlp:1][ksplit:1][rowtile:4][coltile:2]; tile 64x64.
__global__ __launch_bounds__(256) void k2_out(
    const float* __restrict__ P, const float* __restrict__ G,
    const float* __restrict__ W2, const float* __restrict__ W2g,
    char* __restrict__ wsb, float* __restrict__ out)
{
    __shared__ unsigned short sAh[2][4096], sAl[2][4096], sW[2][4096];
    __shared__ float red[256];
    const int bx = blockIdx.x, t = threadIdx.x;
    const int mlp = bx >> 7;
    const int ks  = (bx >> 6) & 1;
    const int m0  = ((bx >> 2) & 15) * 64;
    const int n0  = (bx & 3) * 64;
    const int wv = t >> 6, ln = t & 63;
    const int wr = wv >> 1, wc = wv & 1;

    const unsigned short* ha = (const unsigned short*)(wsb + (mlp ? B_HGH : B_H1H));
    const unsigned short* la = (const unsigned short*)(wsb + (mlp ? B_HGL : B_H1L));
    const float* wt = mlp ? W2g : W2;    // fp32 [512][256]
    const float* Y  = mlp ? G : P;
    const float* cm = (const float*)(wsb + B_CM) + mlp * 4096;
    const int kb = ks * 256;

    float wR[2][16];
    auto loadW = [&](int rb, int c) {
        #pragma unroll
        for (int j = 0; j < 16; ++j)
            wR[rb][j] = wt[(size_t)(kb + c * 64 + wv * 16 + j) * DX + n0 + ln];
    };
    auto writeW = [&](int rb, int b) {
        #pragma unroll
        for (int s = 0; s < 2; ++s) {
            const int byo = ln * 128 + ((((2 * wv + s) ^ (ln & 7))) << 4);
            *(ushort4*)((char*)sW[b] + byo) =
                make_ushort4(bf16rne(wR[rb][s*8+0]), bf16rne(wR[rb][s*8+1]),
                             bf16rne(wR[rb][s*8+2]), bf16rne(wR[rb][s*8+3]));
            *(ushort4*)((char*)sW[b] + byo + 8) =
                make_ushort4(bf16rne(wR[rb][s*8+4]), bf16rne(wR[rb][s*8+5]),
                             bf16rne(wR[rb][s*8+6]), bf16rne(wR[rb][s*8+7]));
        }
    };

    stage_bf16(ha, m0, kb, 512, sAh[0], wv, ln);
    stage_bf16(la, m0, kb, 512, sAl[0], wv, ln);
    loadW(0, 0);
    writeW(0, 0);
    asm volatile("s_waitcnt vmcnt(0)" ::: "memory");
    __syncthreads();

    f32x4 zero = {0.f, 0.f, 0.f, 0.f};
    f32x4 acc[2][2] = {{zero, zero}, {zero, zero}};

    #pragma unroll
    for (int c = 0; c < 4; ++c) {
        const int b = c & 1;
        if (c + 1 < 4) {
            stage_bf16(ha, m0, kb + (c + 1) * 64, 512, sAh[1 - b], wv, ln);
            stage_bf16(la, m0, kb + (c + 1) * 64, 512, sAl[1 - b], wv, ln);
            loadW(1 - b, c + 1);
        }
        #pragma unroll
        for (int kc = 0; kc < 64; kc += 32) {
            uint4 fh[2], fl[2], fw[2];
            #pragma unroll
            for (int s = 0; s < 2; ++s) {
                const int ra = 32 * wr + 16 * s + (ln & 15);
                fh[s] = ldsfrag(sAh[b], ra, kc, ln);
                fl[s] = ldsfrag(sAl[b], ra, kc, ln);
                fw[s] = ldsfrag(sW[b], 32 * wc + 16 * s + (ln & 15), kc, ln);
            }
            #pragma unroll
            for (int sr = 0; sr < 2; ++sr)
                #pragma unroll
                for (int sc = 0; sc < 2; ++sc) {
                    acc[sr][sc] = MFMA(fh[sr], fw[sc], acc[sr][sc]);
                    acc[sr][sc] = MFMA(fl[sr], fw[sc], acc[sr][sc]);
                }
        }
        if (c + 1 < 4) writeW(1 - b, 1 - b);
        asm volatile("s_waitcnt vmcnt(0)" ::: "memory");
        __syncthreads();
    }

    float part = 0.f;
    #pragma unroll
    for (int sc = 0; sc < 2; ++sc) {
        const int C = n0 + 32 * wc + 16 * sc + (ln & 15);
        float s = 0.f;
        #pragma unroll
        for (int st = 0; st < 16; ++st) s += cm[st * 256 + C];
        const float e = s * (1.0f / NR);
        #pragma unroll
        for (int sr = 0; sr < 2; ++sr)
            #pragma unroll
            for (int r = 0; r < 4; ++r) {
                const int R = m0 + 32 * wr + 16 * sr + 4 * (ln >> 4) + r;
                part += acc[sr][sc][r] * (Y[(size_t)R * DX + C] - e);
            }
    }
    red[t] = part;
    __syncthreads();
    #pragma unroll
    for (int sft = 128; sft > 0; sft >>= 1) {
        if (t < sft) red[t] += red[t + sft];
        __syncthreads();
    }

    if (t == 0) {
        unsigned long long* tot = (unsigned long long*)(wsb + B_TOT);
        unsigned* ctr = (unsigned*)(wsb + B_CTR);
        const long long ll = llrint((double)red[0] * FIXSCALE);
        atomicAdd(tot, (unsigned long long)ll);
        asm volatile("s_waitcnt vmcnt(0)" ::: "memory");  // total-add ack before ctr-add
        const unsigned prev = atomicAdd(ctr, 1u);
        if (prev == 255u) {
            const unsigned long long s = atomicAdd(tot, 0ull);  // coherent read
            out[0] = (float)((double)(long long)s * (1.0 / FIXSCALE) * (1.0 / NR));
        }
    }
}

// ---------------------------------------------------------------------------
extern "C" void kernel_launch(void* const* d_in, const int* in_sizes, int n_in,
                              void* d_out, int out_size, void* d_ws, size_t ws_size,
                              hipStream_t stream)
{
    const float* H   = (const float*)d_in[0];
    const float* P   = (const float*)d_in[1];
    const float* G   = (const float*)d_in[2];
    const float* W1  = (const float*)d_in[3];
    const float* b1  = (const float*)d_in[4];
    const float* W2  = (const float*)d_in[5];
    // d_in[6] = b2: provably zero contribution
    const float* W1g = (const float*)d_in[7];
    const float* b1g = (const float*)d_in[8];
    const float* W2g = (const float*)d_in[9];
    // d_in[10] = b2g: unused
    char* wsb = (char*)d_ws;
    float* out = (float*)d_out;

    hipLaunchKernelGGL(k1_hidden, dim3(256), dim3(256), 0, stream,
                       H, P, G, W1, b1, W1g, b1g, wsb);
    hipLaunchKernelGGL(k2_out,    dim3(256), dim3(256), 0, stream,
                       P, G, W2, W2g, wsb, out);
}